// Round 4
// baseline (811.068 us; speedup 1.0000x reference)
//
#include <hip/hip_runtime.h>

#define ALPHA 0.2f

// Cross-block state in module-owned device globals (d_ws avoided).
__device__ float g_acc[9216];   // E[rep][n][ch] (1024) | S[rep][n][ch][v] (8192)
__device__ float g_ctx[1024];   // ctx[n][ch][v]  (n*512 + ch*8 + v)

__global__ void k_zero() {
  int i = blockIdx.x * 256 + threadIdx.x;
  if (i < 9216) g_acc[i] = 0.f;
}

// =====================================================================
// Phase 1: per-(n,h,w) tile of 64 tokens (channel c) x 64 d.
// K GEMM -> affine+LReLU -> exp (clamped); V GEMM;
// per-channel sums E = sum(e), S[v] = sum(e * V[head(v)]) -> atomicAdd.
// =====================================================================
__global__ __launch_bounds__(256) void k_kv(
    const float* __restrict__ x,
    const float* __restrict__ Wk, const float* __restrict__ sk, const float* __restrict__ bk,
    const float* __restrict__ Wv, const float* __restrict__ sv, const float* __restrict__ bv)
{
  __shared__ __align__(16) float WL[64 * 64];          // weights; later reduce scratch
  __shared__ __align__(16) float kvL[2 * 64 * 65];     // [e^K | V][ci][65]
  __shared__ __align__(16) float xt[64 * 64];          // [d][ci]

  const int tid = threadIdx.x;
  const int bid = blockIdx.x;
  const int n  = bid >> 12;
  const int hw = bid & 4095;

  const int ci0 = (tid & 31) * 2;   // 2 tokens per thread
  const int e0  = (tid >> 5) * 8;   // 8 channels (one head) per thread

  const float* xrow = x + (size_t)n * 16777216u + (size_t)hw * 64u;

  // stage x tile (d-major, ci contiguous): 4096 floats
  #pragma unroll
  for (int i = 0; i < 4; ++i) {
    int idx = tid + i * 256;              // 0..1023
    int d = idx >> 4, c4 = (idx & 15) * 4;
    *(float4*)&xt[d * 64 + c4] = *(const float4*)(xrow + (size_t)d * 262144u + c4);
  }

  for (int p = 0; p < 2; ++p) {
    const float* Wp = (p == 0) ? Wk : Wv;
    const float* sp = (p == 0) ? sk : sv;
    const float* bp = (p == 0) ? bk : bv;

    __syncthreads();  // xt ready (p==0); prev phase done with WL (p==1)
    #pragma unroll
    for (int i = 0; i < 4; ++i) {
      int idx = tid + i * 256;
      int d = idx >> 4, e4 = (idx & 15) * 4;
      *(float4*)&WL[d * 64 + e4] = *(const float4*)(Wp + d * 64 + e4);
    }
    __syncthreads();

    float acc0[8], acc1[8];
    #pragma unroll
    for (int j = 0; j < 8; ++j) { acc0[j] = 0.f; acc1[j] = 0.f; }

    #pragma unroll 4
    for (int d = 0; d < 64; ++d) {
      float2 xv = *(const float2*)&xt[d * 64 + ci0];
      float4 wa = *(const float4*)&WL[d * 64 + e0];
      float4 wb = *(const float4*)&WL[d * 64 + e0 + 4];
      float w[8] = {wa.x, wa.y, wa.z, wa.w, wb.x, wb.y, wb.z, wb.w};
      #pragma unroll
      for (int j = 0; j < 8; ++j) { acc0[j] += xv.x * w[j]; acc1[j] += xv.y * w[j]; }
    }

    float sv8[8], bv8[8];
    *(float4*)&sv8[0] = *(const float4*)(sp + e0);
    *(float4*)&sv8[4] = *(const float4*)(sp + e0 + 4);
    *(float4*)&bv8[0] = *(const float4*)(bp + e0);
    *(float4*)&bv8[4] = *(const float4*)(bp + e0 + 4);

    float* dst = &kvL[p * 4160];
    #pragma unroll
    for (int j = 0; j < 8; ++j) {
      float y0 = acc0[j] * sv8[j] + bv8[j];
      float y1 = acc1[j] * sv8[j] + bv8[j];
      y0 = (y0 >= 0.f) ? y0 : ALPHA * y0;
      y1 = (y1 >= 0.f) ? y1 : ALPHA * y1;
      if (p == 0) { y0 = __expf(fminf(y0, 60.f)); y1 = __expf(fminf(y1, 60.f)); }
      dst[ci0 * 65 + e0 + j]       = y0;
      dst[(ci0 + 1) * 65 + e0 + j] = y1;
    }
  }
  __syncthreads();  // kvL complete; WL free for scratch

  {
    float* pE = WL;          // [4][64]
    float* pS = WL + 256;    // [4][64][8]
    const int ch = tid & 63;
    const int tq = tid >> 6;
    const int a8 = ch & ~7;
    const float* eK = &kvL[0];
    const float* vV = &kvL[4160];

    float E = 0.f;
    float S[8];
    #pragma unroll
    for (int v = 0; v < 8; ++v) S[v] = 0.f;
    for (int t = tq * 16; t < tq * 16 + 16; ++t) {
      float e = eK[t * 65 + ch];
      E += e;
      #pragma unroll
      for (int v = 0; v < 8; ++v) S[v] += e * vV[t * 65 + a8 + v];
    }
    pE[tq * 64 + ch] = E;
    #pragma unroll
    for (int v = 0; v < 8; ++v) pS[(tq * 64 + ch) * 8 + v] = S[v];
    __syncthreads();

    if (tid < 64) {
      const int rep = hw & 7;
      float E4 = pE[tid] + pE[64 + tid] + pE[128 + tid] + pE[192 + tid];
      atomicAdd(&g_acc[(rep * 2 + n) * 64 + tid], E4);
      #pragma unroll
      for (int v = 0; v < 8; ++v) {
        float S4 = pS[tid * 8 + v] + pS[(64 + tid) * 8 + v]
                 + pS[(128 + tid) * 8 + v] + pS[(192 + tid) * 8 + v];
        atomicAdd(&g_acc[1024 + ((rep * 2 + n) * 64 + tid) * 8 + v], S4);
      }
    }
  }
}

// =====================================================================
// Phase 1.5: reduce replicas -> guarded ctx (NaN structurally impossible).
// =====================================================================
__global__ __launch_bounds__(256) void k_ctx() {
  int i = blockIdx.x * 256 + threadIdx.x;   // i = n*512 + ch*8 + v
  if (i >= 1024) return;
  int n = i >> 9, ch = (i & 511) >> 3, v = i & 7;
  float l = 0.f, S = 0.f;
  #pragma unroll
  for (int r = 0; r < 8; ++r) {
    l += g_acc[(r * 2 + n) * 64 + ch];
    S += g_acc[1024 + ((r * 2 + n) * 64 + ch) * 8 + v];
  }
  float c = (l > 0.f) ? (S / l) : 0.f;
  if (!(__builtin_fabsf(c) < 1e30f)) c = 0.f;   // catches NaN/inf too
  g_ctx[i] = c;
}

// =====================================================================
// Phase 2: block = (n, h', w'). Q tokens: c_t=(c'&7)*8+(h'>>3),
// h_t=(h'&7)*8+(w'>>3) fixed, w_t=(w'&7)*8+v''. Recompute Q, agg,
// rep GEMM + affine + LReLU, residual add. WrL overlays xql (staged
// after Q-GEMM) to keep LDS ~68 KB -> 2 blocks/CU.
// =====================================================================
__global__ __launch_bounds__(256) void k_att(
    const float* __restrict__ x,
    const float* __restrict__ Wq, const float* __restrict__ sq, const float* __restrict__ bq,
    const float* __restrict__ Wr, const float* __restrict__ sr, const float* __restrict__ br,
    float* __restrict__ out)
{
  __shared__ __align__(16) float WqL[64 * 64];   // [d][ch]
  __shared__ __align__(16) float xw[64 * 64];    // xql [d][tok], then WrL [e][d]
  __shared__ float qL[64 * 65];                  // [tok][ch]
  __shared__ float aggL[64 * 65];                // [c'][e]
  __shared__ float ctxL[64 * 9];                 // [a*8+k][v]
  __shared__ float srL[64], brL[64];

  const int tid = threadIdx.x;
  const int bid = blockIdx.x;
  const int n  = bid >> 12;
  const int hwp = bid & 4095;
  const int hp = hwp >> 6, wp = hwp & 63;

  const int jc    = hp >> 3;
  const int h_t   = (hp & 7) * 8 + (wp >> 3);
  const int wbase = (wp & 7) * 8;

  #pragma unroll
  for (int i = 0; i < 4; ++i) {
    int idx = tid + i * 256;
    int r = idx >> 4, c4 = (idx & 15) * 4;
    *(float4*)&WqL[r * 64 + c4] = *(const float4*)(Wq + r * 64 + c4);
  }
  if (tid < 64) { srL[tid] = sr[tid]; brL[tid] = br[tid]; }

  for (int i = tid; i < 512; i += 256) {
    int ch = i >> 3, v = i & 7;
    ctxL[ch * 9 + v] = g_ctx[n * 512 + ch * 8 + v];
  }

  // gather x for the 64 needed tokens: xw[d][tok], tok = v''*8 + c'low
  {
    const size_t xb = (size_t)n * 16777216u + (size_t)h_t * 4096u;
    #pragma unroll
    for (int i = 0; i < 16; ++i) {
      int idx = tid + i * 256;
      int d = idx >> 6, tok = idx & 63;
      int vpp = tok >> 3, cl = tok & 7;
      xw[d * 64 + tok] = x[xb + (size_t)d * 262144u + (size_t)(wbase + vpp) * 64u + (cl * 8 + jc)];
    }
  }
  __syncthreads();

  // Q GEMM (2 tok x 8 ch per thread) + affine + LReLU + softmax over head
  {
    const int tok0 = (tid & 31) * 2;
    const int ch0  = (tid >> 5) * 8;
    float acc0[8], acc1[8];
    #pragma unroll
    for (int j = 0; j < 8; ++j) { acc0[j] = 0.f; acc1[j] = 0.f; }
    #pragma unroll 4
    for (int d = 0; d < 64; ++d) {
      float2 xv = *(const float2*)&xw[d * 64 + tok0];
      float4 wa = *(const float4*)&WqL[d * 64 + ch0];
      float4 wb = *(const float4*)&WqL[d * 64 + ch0 + 4];
      float w[8] = {wa.x, wa.y, wa.z, wa.w, wb.x, wb.y, wb.z, wb.w};
      #pragma unroll
      for (int j = 0; j < 8; ++j) { acc0[j] += xv.x * w[j]; acc1[j] += xv.y * w[j]; }
    }
    float sv8[8], bv8[8];
    *(float4*)&sv8[0] = *(const float4*)(sq + ch0);
    *(float4*)&sv8[4] = *(const float4*)(sq + ch0 + 4);
    *(float4*)&bv8[0] = *(const float4*)(bq + ch0);
    *(float4*)&bv8[4] = *(const float4*)(bq + ch0 + 4);
    #pragma unroll
    for (int i = 0; i < 2; ++i) {
      float* a = (i == 0) ? acc0 : acc1;
      float mx = -3.0e38f;
      #pragma unroll
      for (int j = 0; j < 8; ++j) {
        float y = a[j] * sv8[j] + bv8[j];
        y = (y >= 0.f) ? y : ALPHA * y;
        a[j] = y;
        mx = fmaxf(mx, y);
      }
      float sum = 0.f;
      #pragma unroll
      for (int j = 0; j < 8; ++j) { a[j] = __expf(a[j] - mx); sum += a[j]; }
      float inv = 1.f / sum;
      #pragma unroll
      for (int j = 0; j < 8; ++j) qL[(tok0 + i) * 65 + ch0 + j] = a[j] * inv;
    }
  }
  __syncthreads();   // Q-GEMM done with xw -> repurpose as WrL

  #pragma unroll
  for (int i = 0; i < 4; ++i) {
    int idx = tid + i * 256;
    int r = idx >> 4, c4 = (idx & 15) * 4;
    *(float4*)&xw[r * 64 + c4] = *(const float4*)(Wr + r * 64 + c4);
  }

  // agg[c'][e]
  {
    const int cp = tid & 63, eb = tid >> 6;
    const int kk = cp >> 3, cl = cp & 7;
    #pragma unroll
    for (int je = 0; je < 16; ++je) {
      int e = eb * 16 + je;
      int a = e >> 3, vpp = e & 7;
      const float* cx = &ctxL[(a * 8 + kk) * 9];
      const float* qr = &qL[(vpp * 8 + cl) * 65 + a * 8];
      float s = 0.f;
      #pragma unroll
      for (int v = 0; v < 8; ++v) s += cx[v] * qr[v];
      aggL[cp * 65 + e] = s;
    }
  }
  __syncthreads();

  // rep GEMM + residual (lanes = c', coalesced 256B rows)
  {
    const int ci = tid & 63, dq = tid >> 6;
    float accr[16];
    #pragma unroll
    for (int i = 0; i < 16; ++i) accr[i] = 0.f;
    #pragma unroll 4
    for (int e = 0; e < 64; ++e) {
      float av = aggL[ci * 65 + e];
      const float* wr = &xw[e * 64 + dq * 16];
      #pragma unroll
      for (int i = 0; i < 16; ++i) accr[i] += av * wr[i];
    }
    const size_t xb = (size_t)n * 16777216u + (size_t)hwp * 64u + (size_t)ci;
    #pragma unroll
    for (int i = 0; i < 16; ++i) {
      int di = dq * 16 + i;
      float y = accr[i] * srL[di] + brL[di];
      y = (y >= 0.f) ? y : ALPHA * y;
      out[xb + (size_t)di * 262144u] = x[xb + (size_t)di * 262144u] + y;
    }
  }
}

// =====================================================================
extern "C" void kernel_launch(void* const* d_in, const int* in_sizes, int n_in,
                              void* d_out, int out_size, void* d_ws, size_t ws_size,
                              hipStream_t stream)
{
  (void)in_sizes; (void)n_in; (void)out_size; (void)d_ws; (void)ws_size;

  const float* x  = (const float*)d_in[0];
  const float* Wk = (const float*)d_in[1];
  const float* sk = (const float*)d_in[2];
  const float* bk = (const float*)d_in[3];
  const float* Wq = (const float*)d_in[4];
  const float* sq = (const float*)d_in[5];
  const float* bq = (const float*)d_in[6];
  const float* Wv = (const float*)d_in[7];
  const float* sv = (const float*)d_in[8];
  const float* bv = (const float*)d_in[9];
  const float* Wr = (const float*)d_in[10];
  const float* sr = (const float*)d_in[11];
  const float* br = (const float*)d_in[12];
  float* out = (float*)d_out;

  k_zero<<<dim3(36),   dim3(256), 0, stream>>>();
  k_kv  <<<dim3(8192), dim3(256), 0, stream>>>(x, Wk, sk, bk, Wv, sv, bv);
  k_ctx <<<dim3(4),    dim3(256), 0, stream>>>();
  k_att <<<dim3(8192), dim3(256), 0, stream>>>(x, Wq, sq, bq, Wr, sr, br, out);
}